// Round 1
// baseline (131.111 us; speedup 1.0000x reference)
//
#include <hip/hip_runtime.h>
#include <math.h>

#define D 256
#define S 4096
#define BATCH 4
#define RPB 8          // rows per block in band kernel
#define TS 16          // rows per block in decoder
#define DT_CUT 7.0f

// ---------------------------------------------------------------------------
// K1: sinusoidal temporal embedding  emb[b,s,d]
//   w_k[d] = 10000^(2*(d/2+1)/256);  te = t / w_k;  even d -> sin, odd -> cos
// ---------------------------------------------------------------------------
__global__ __launch_bounds__(256) void emb_kernel(const float* __restrict__ t,
                                                  float* __restrict__ emb) {
    int bs = blockIdx.x;
    int d  = threadIdx.x;
    float tv = t[bs];
    int k = d >> 1;
    float w_inv = powf(10000.0f, -2.0f * (float)(k + 1) / 256.0f);
    float te = tv * w_inv;
    float v = (d & 1) ? cosf(te) : sinf(te);
    emb[(size_t)bs * D + d] = v;
}

// ---------------------------------------------------------------------------
// K2: banded causal SE-kernel matmul + fused LayerNorm
//   hidden[b,i,d] = LN( sum_{j<=i} exp(-(ti-tj)^2/2) * emb[b,j,d] )
// One block = 8 consecutive rows i0..i0+7, 256 threads = d.
// Band start jmin = lower_bound(t[i0] - DT_CUT) (times sorted ascending).
// ---------------------------------------------------------------------------
__global__ __launch_bounds__(256) void band_ln_kernel(
    const float* __restrict__ t, const float* __restrict__ emb,
    const float* __restrict__ gamma, const float* __restrict__ beta,
    float* __restrict__ hidden) {
    int blk = blockIdx.x;
    int b   = blk / (S / RPB);
    int i0  = (blk % (S / RPB)) * RPB;
    int d   = threadIdx.x;
    const float* tb = t + b * S;

    float ti[RPB];
#pragma unroll
    for (int r = 0; r < RPB; ++r) ti[r] = tb[i0 + r];

    // binary search: first j with tb[j] >= tb[i0] - DT_CUT (uniform across block)
    float tcut = ti[0] - DT_CUT;
    int lo = 0, hi = i0;
    while (lo < hi) {
        int mid = (lo + hi) >> 1;
        if (tb[mid] < tcut) lo = mid + 1; else hi = mid;
    }
    int jmin = lo;
    int jmax = i0 + RPB - 1;

    __shared__ float s_sc[256][RPB];   // scores chunk, jj-major
    float acc[RPB];
#pragma unroll
    for (int r = 0; r < RPB; ++r) acc[r] = 0.0f;
    const float* eb = emb + (size_t)b * S * D;

    for (int j0 = jmin; j0 <= jmax; j0 += 256) {
        int j = j0 + d;
        __syncthreads();               // protect prior iteration's reads
        float tj = (j <= jmax) ? tb[j] : 0.0f;
#pragma unroll
        for (int r = 0; r < RPB; ++r) {
            float dt = ti[r] - tj;
            float sc = expf(-0.5f * dt * dt);
            sc = (j <= i0 + r) ? sc : 0.0f;   // causal mask (j<=i)
            s_sc[d][r] = sc;
        }
        __syncthreads();
        int n = min(256, jmax - j0 + 1);
        const float* ebase = eb + (size_t)j0 * D + d;
        for (int jj = 0; jj < n; ++jj) {
            float4 s0 = *(const float4*)&s_sc[jj][0];   // uniform addr: LDS broadcast
            float4 s1 = *(const float4*)&s_sc[jj][4];
            float ev = ebase[(size_t)jj * D];           // coalesced across d
            acc[0] = fmaf(s0.x, ev, acc[0]);
            acc[1] = fmaf(s0.y, ev, acc[1]);
            acc[2] = fmaf(s0.z, ev, acc[2]);
            acc[3] = fmaf(s0.w, ev, acc[3]);
            acc[4] = fmaf(s1.x, ev, acc[4]);
            acc[5] = fmaf(s1.y, ev, acc[5]);
            acc[6] = fmaf(s1.z, ev, acc[6]);
            acc[7] = fmaf(s1.w, ev, acc[7]);
        }
    }

    // fused LayerNorm over d (per row)
    __shared__ float s_part[RPB][4][2];
    __shared__ float s_mu[RPB], s_rstd[RPB];
    int lane = d & 63, wave = d >> 6;
#pragma unroll
    for (int r = 0; r < RPB; ++r) {
        float sum = acc[r], sq = acc[r] * acc[r];
        for (int off = 32; off > 0; off >>= 1) {
            sum += __shfl_down(sum, off);
            sq  += __shfl_down(sq, off);
        }
        if (lane == 0) { s_part[r][wave][0] = sum; s_part[r][wave][1] = sq; }
    }
    __syncthreads();
    if (d < RPB) {
        float sum = 0.0f, sq = 0.0f;
        for (int w = 0; w < 4; ++w) { sum += s_part[d][w][0]; sq += s_part[d][w][1]; }
        float mu  = sum * (1.0f / D);
        float var = fmaxf(sq * (1.0f / D) - mu * mu, 0.0f);
        s_mu[d]   = mu;
        s_rstd[d] = rsqrtf(var + 1e-6f);
    }
    __syncthreads();
    float g = gamma[d], be = beta[d];
#pragma unroll
    for (int r = 0; r < RPB; ++r) {
        float h = (acc[r] - s_mu[r]) * s_rstd[r] * g + be;
        hidden[((size_t)(b * S + i0 + r)) * D + d] = h;
    }
}

// ---------------------------------------------------------------------------
// K3: transpose W_in (256x256) so decoder reads coalesce: Wt[d][e] = W[e][d]
// ---------------------------------------------------------------------------
__global__ __launch_bounds__(256) void transpose_kernel(const float* __restrict__ W,
                                                        float* __restrict__ Wt) {
    int e = blockIdx.x, d = threadIdx.x;
    Wt[d * D + e] = W[e * D + d];
}

// ---------------------------------------------------------------------------
// K4: decoder  out[s] = softplus( sum_e relu(sum_d h[s,d]*W[e,d]) * w_t[e] + b )
// One block = TS rows, 256 threads = e.
// ---------------------------------------------------------------------------
__global__ __launch_bounds__(256) void decoder_kernel(
    const float* __restrict__ hidden, const float* __restrict__ Wt,
    const float* __restrict__ w_t, const float* __restrict__ b_t,
    float* __restrict__ out) {
    int blk = blockIdx.x;
    int e   = threadIdx.x;
    size_t row0 = (size_t)blk * TS;

    __shared__ float h[TS][D];
#pragma unroll
    for (int r = 0; r < TS; ++r) h[r][e] = hidden[(row0 + r) * D + e];
    __syncthreads();

    float wt_e = w_t[e];
    float acc[TS];
#pragma unroll
    for (int r = 0; r < TS; ++r) acc[r] = 0.0f;

    for (int dd = 0; dd < D; dd += 4) {
        float w0 = Wt[(dd + 0) * D + e];
        float w1 = Wt[(dd + 1) * D + e];
        float w2 = Wt[(dd + 2) * D + e];
        float w3 = Wt[(dd + 3) * D + e];
#pragma unroll
        for (int r = 0; r < TS; ++r) {
            float4 hv = *(const float4*)&h[r][dd];   // uniform addr: broadcast
            acc[r] = fmaf(hv.x, w0, fmaf(hv.y, w1, fmaf(hv.z, w2, fmaf(hv.w, w3, acc[r]))));
        }
    }

    __shared__ float s_part[TS][4];
    int lane = e & 63, wave = e >> 6;
#pragma unroll
    for (int r = 0; r < TS; ++r) {
        float p = fmaxf(acc[r], 0.0f) * wt_e;
        for (int off = 32; off > 0; off >>= 1) p += __shfl_down(p, off);
        if (lane == 0) s_part[r][wave] = p;
    }
    __syncthreads();
    if (e < TS) {
        float tot = s_part[e][0] + s_part[e][1] + s_part[e][2] + s_part[e][3] + b_t[0];
        float o = fmaxf(tot, 0.0f) + log1pf(expf(-fabsf(tot)));  // softplus
        out[row0 + e] = o;
    }
}

// ---------------------------------------------------------------------------
extern "C" void kernel_launch(void* const* d_in, const int* in_sizes, int n_in,
                              void* d_out, int out_size, void* d_ws, size_t ws_size,
                              hipStream_t stream) {
    // inputs: 0 event_type(i32) 1 event_time(f32) 2 arrival_times(f32)
    //         3 W_in 4 w_t 5 b_t 6 ln_gamma 7 ln_beta
    const float* t   = (const float*)d_in[1];
    const float* W   = (const float*)d_in[3];
    const float* wt  = (const float*)d_in[4];
    const float* bt  = (const float*)d_in[5];
    const float* gam = (const float*)d_in[6];
    const float* bet = (const float*)d_in[7];
    float* out = (float*)d_out;

    char* ws = (char*)d_ws;
    float* emb    = (float*)ws;                   // 4*4096*256*4 = 16 MiB
    float* hidden = (float*)(ws + (size_t)16777216);   // 16 MiB
    float* Wt     = (float*)(ws + (size_t)33554432);   // 256 KiB

    emb_kernel<<<dim3(BATCH * S), dim3(256), 0, stream>>>(t, emb);
    transpose_kernel<<<dim3(256), dim3(256), 0, stream>>>(W, Wt);
    band_ln_kernel<<<dim3(BATCH * S / RPB), dim3(256), 0, stream>>>(t, emb, gam, bet, hidden);
    decoder_kernel<<<dim3(BATCH * S / TS), dim3(256), 0, stream>>>(hidden, Wt, wt, bt, out);
}

// Round 2
// 110.460 us; speedup vs baseline: 1.1870x; 1.1870x over previous
//
#include <hip/hip_runtime.h>
#include <math.h>

#define D 256
#define S 4096
#define BATCH 4
#define RPB 16         // rows per block in band kernel
#define TS 16          // rows per block in decoder
#define DT_CUT 7.0f

// ---------------------------------------------------------------------------
// K1: sinusoidal temporal embedding. 2 rows/block; thread=(rh,k) computes the
// (sin,cos) pair for frequency k via one __sincosf, float2 store.
// ---------------------------------------------------------------------------
__global__ __launch_bounds__(256) void emb_kernel(const float* __restrict__ t,
                                                  float* __restrict__ emb) {
    int tid = threadIdx.x;
    int rh  = tid >> 7;        // 0..1: which row of this block
    int k   = tid & 127;       // frequency index
    int row = blockIdx.x * 2 + rh;
    float tv = t[row];
    const float c2 = -0.1038102552f;            // -2*log2(10000)/256
    float w_inv = exp2f(c2 * (float)(k + 1));   // 10000^(-2(k+1)/256)
    float te = tv * w_inv;
    float sn, cs;
    __sincosf(te, &sn, &cs);
    *(float2*)&emb[(size_t)row * D + 2 * k] = make_float2(sn, cs);
}

// ---------------------------------------------------------------------------
// K2: banded causal SE-kernel matmul + fused LayerNorm. 16 rows/block,
// 256 threads = d. Band start via binary search (times sorted ascending).
// jj loop unrolled x4: 4 independent emb loads in flight.
// ---------------------------------------------------------------------------
__global__ __launch_bounds__(256) void band_ln_kernel(
    const float* __restrict__ t, const float* __restrict__ emb,
    const float* __restrict__ gamma, const float* __restrict__ beta,
    float* __restrict__ hidden) {
    int blk = blockIdx.x;
    int b   = blk / (S / RPB);
    int i0  = (blk % (S / RPB)) * RPB;
    int d   = threadIdx.x;
    const float* tb = t + b * S;

    float ti[RPB];
#pragma unroll
    for (int r = 0; r < RPB; ++r) ti[r] = tb[i0 + r];

    // first j with tb[j] >= tb[i0] - DT_CUT  (uniform across block)
    float tcut = ti[0] - DT_CUT;
    int lo = 0, hi = i0;
    while (lo < hi) {
        int mid = (lo + hi) >> 1;
        if (tb[mid] < tcut) lo = mid + 1; else hi = mid;
    }
    int jmin = lo;
    int jmax = i0 + RPB - 1;

    __shared__ float s_sc[256][RPB];   // 16 KiB score chunk, jj-major
    float acc[RPB];
#pragma unroll
    for (int r = 0; r < RPB; ++r) acc[r] = 0.0f;
    const float* eb = emb + (size_t)b * S * D;

    for (int j0 = jmin; j0 <= jmax; j0 += 256) {
        int j = j0 + d;
        __syncthreads();               // protect prior iteration's reads
        float tj = (j <= jmax) ? tb[j] : 0.0f;
#pragma unroll
        for (int r = 0; r < RPB; ++r) {
            float dt = ti[r] - tj;
            float sc = expf(-0.5f * dt * dt);
            sc = (j <= i0 + r) ? sc : 0.0f;   // causal mask
            s_sc[d][r] = sc;
        }
        __syncthreads();
        int n = min(256, jmax - j0 + 1);
        const float* ebase = eb + (size_t)j0 * D + d;

        int jj = 0;
        for (; jj + 4 <= n; jj += 4) {
            float ev0 = ebase[(jj + 0) * D];
            float ev1 = ebase[(jj + 1) * D];
            float ev2 = ebase[(jj + 2) * D];
            float ev3 = ebase[(jj + 3) * D];
#pragma unroll
            for (int u = 0; u < 4; ++u) {
                float ev = (u == 0) ? ev0 : (u == 1) ? ev1 : (u == 2) ? ev2 : ev3;
#pragma unroll
                for (int q = 0; q < RPB / 4; ++q) {
                    float4 sq = *(const float4*)&s_sc[jj + u][4 * q];
                    acc[4 * q + 0] = fmaf(sq.x, ev, acc[4 * q + 0]);
                    acc[4 * q + 1] = fmaf(sq.y, ev, acc[4 * q + 1]);
                    acc[4 * q + 2] = fmaf(sq.z, ev, acc[4 * q + 2]);
                    acc[4 * q + 3] = fmaf(sq.w, ev, acc[4 * q + 3]);
                }
            }
        }
        for (; jj < n; ++jj) {
            float ev = ebase[jj * D];
#pragma unroll
            for (int q = 0; q < RPB / 4; ++q) {
                float4 sq = *(const float4*)&s_sc[jj][4 * q];
                acc[4 * q + 0] = fmaf(sq.x, ev, acc[4 * q + 0]);
                acc[4 * q + 1] = fmaf(sq.y, ev, acc[4 * q + 1]);
                acc[4 * q + 2] = fmaf(sq.z, ev, acc[4 * q + 2]);
                acc[4 * q + 3] = fmaf(sq.w, ev, acc[4 * q + 3]);
            }
        }
    }

    // fused LayerNorm over d (per row)
    __shared__ float s_part[RPB][4][2];
    __shared__ float s_mu[RPB], s_rstd[RPB];
    int lane = d & 63, wave = d >> 6;
#pragma unroll
    for (int r = 0; r < RPB; ++r) {
        float sum = acc[r], sq = acc[r] * acc[r];
        for (int off = 32; off > 0; off >>= 1) {
            sum += __shfl_down(sum, off);
            sq  += __shfl_down(sq, off);
        }
        if (lane == 0) { s_part[r][wave][0] = sum; s_part[r][wave][1] = sq; }
    }
    __syncthreads();
    if (d < RPB) {
        float sum = 0.0f, sq = 0.0f;
        for (int w = 0; w < 4; ++w) { sum += s_part[d][w][0]; sq += s_part[d][w][1]; }
        float mu  = sum * (1.0f / D);
        float var = fmaxf(sq * (1.0f / D) - mu * mu, 0.0f);
        s_mu[d]   = mu;
        s_rstd[d] = rsqrtf(var + 1e-6f);
    }
    __syncthreads();
    float g = gamma[d], be = beta[d];
#pragma unroll
    for (int r = 0; r < RPB; ++r) {
        float h = (acc[r] - s_mu[r]) * s_rstd[r] * g + be;
        hidden[((size_t)(b * S + i0 + r)) * D + d] = h;
    }
}

// ---------------------------------------------------------------------------
// K3: repack W_in: Wt4[dq][e] = float4{ W[e][4dq..4dq+3] }  (dq = d/4)
// ---------------------------------------------------------------------------
__global__ __launch_bounds__(256) void transpose_kernel(const float* __restrict__ W,
                                                        float* __restrict__ Wt4) {
    int e = blockIdx.x, dd = threadIdx.x;
    // layout: [(dd>>2)][e][dd&3]  ->  index (dd>>2)*1024 + e*4 + (dd&3)
    Wt4[(dd >> 2) * 1024 + e * 4 + (dd & 3)] = W[e * D + dd];
}

// ---------------------------------------------------------------------------
// K4: decoder  out[s] = softplus( sum_e relu(sum_d h[s,d]*W[e,d]) * w_t[e] + b )
// TS rows/block, thread = e. hidden read via wave-uniform addresses (scalar
// loads, no LDS); W via one coalesced float4 per 64 FMA.
// ---------------------------------------------------------------------------
__global__ __launch_bounds__(256) void decoder_kernel(
    const float* __restrict__ hidden, const float4* __restrict__ Wt4,
    const float* __restrict__ w_t, const float* __restrict__ b_t,
    float* __restrict__ out) {
    int blk = blockIdx.x;
    int e   = threadIdx.x;
    size_t row0 = (size_t)blk * TS;
    const float4* hbase = (const float4*)(hidden + row0 * D);  // [r*64 + dq]

    float acc[TS];
#pragma unroll
    for (int r = 0; r < TS; ++r) acc[r] = 0.0f;

    for (int dq = 0; dq < 64; ++dq) {
        float4 wv = Wt4[dq * 256 + e];     // coalesced 16B/lane
#pragma unroll
        for (int r = 0; r < TS; ++r) {
            float4 hv = hbase[r * 64 + dq];   // uniform -> scalar load
            acc[r] = fmaf(hv.x, wv.x,
                     fmaf(hv.y, wv.y,
                     fmaf(hv.z, wv.z,
                     fmaf(hv.w, wv.w, acc[r]))));
        }
    }

    __shared__ float s_part[TS][4];
    int lane = e & 63, wave = e >> 6;
    float wt_e = w_t[e];
#pragma unroll
    for (int r = 0; r < TS; ++r) {
        float p = fmaxf(acc[r], 0.0f) * wt_e;
        for (int off = 32; off > 0; off >>= 1) p += __shfl_down(p, off);
        if (lane == 0) s_part[r][wave] = p;
    }
    __syncthreads();
    if (e < TS) {
        float tot = s_part[e][0] + s_part[e][1] + s_part[e][2] + s_part[e][3] + b_t[0];
        float o = fmaxf(tot, 0.0f) + log1pf(expf(-fabsf(tot)));  // softplus
        out[row0 + e] = o;
    }
}

// ---------------------------------------------------------------------------
extern "C" void kernel_launch(void* const* d_in, const int* in_sizes, int n_in,
                              void* d_out, int out_size, void* d_ws, size_t ws_size,
                              hipStream_t stream) {
    // inputs: 0 event_type(i32) 1 event_time(f32) 2 arrival_times(f32)
    //         3 W_in 4 w_t 5 b_t 6 ln_gamma 7 ln_beta
    const float* t   = (const float*)d_in[1];
    const float* W   = (const float*)d_in[3];
    const float* wt  = (const float*)d_in[4];
    const float* bt  = (const float*)d_in[5];
    const float* gam = (const float*)d_in[6];
    const float* bet = (const float*)d_in[7];
    float* out = (float*)d_out;

    char* ws = (char*)d_ws;
    float* emb    = (float*)ws;                        // 16 MiB
    float* hidden = (float*)(ws + (size_t)16777216);   // 16 MiB
    float* Wt4    = (float*)(ws + (size_t)33554432);   // 256 KiB

    emb_kernel<<<dim3(BATCH * S / 2), dim3(256), 0, stream>>>(t, emb);
    transpose_kernel<<<dim3(256), dim3(256), 0, stream>>>(W, Wt4);
    band_ln_kernel<<<dim3(BATCH * S / RPB), dim3(256), 0, stream>>>(t, emb, gam, bet, hidden);
    decoder_kernel<<<dim3(BATCH * S / TS), dim3(256), 0, stream>>>(
        hidden, (const float4*)Wt4, wt, bt, out);
}

// Round 3
// 74.269 us; speedup vs baseline: 1.7654x; 1.4873x over previous
//
#include <hip/hip_runtime.h>
#include <math.h>

#define D 256
#define S 4096
#define BATCH 4
#define RPB 16         // rows per block in band kernel
#define JC 64          // j-chunk size in band kernel
#define DT_CUT 7.0f

typedef __attribute__((ext_vector_type(8))) short short8;
typedef __attribute__((ext_vector_type(4))) float f32x4;

static __device__ __forceinline__ unsigned short f2bf(float x) {
    unsigned int u = __float_as_uint(x);
    unsigned int r = (u + 0x7FFFu + ((u >> 16) & 1u)) >> 16;   // RNE
    return (unsigned short)r;
}

// ---------------------------------------------------------------------------
// K1: sinusoidal temporal embedding (f32). 2 rows/block, one __sincosf per
// (row, k) pair, float2 store.
// ---------------------------------------------------------------------------
__global__ __launch_bounds__(256) void emb_kernel(const float* __restrict__ t,
                                                  float* __restrict__ emb) {
    int tid = threadIdx.x;
    int rh  = tid >> 7;
    int k   = tid & 127;
    int row = blockIdx.x * 2 + rh;
    float tv = t[row];
    const float c2 = -0.1038102552f;            // -2*log2(10000)/256
    float w_inv = exp2f(c2 * (float)(k + 1));
    float te = tv * w_inv;
    float sn, cs;
    __sincosf(te, &sn, &cs);
    *(float2*)&emb[(size_t)row * D + 2 * k] = make_float2(sn, cs);
}

// ---------------------------------------------------------------------------
// K2: W -> bf16 (row-major [e][d], same layout)
// ---------------------------------------------------------------------------
__global__ __launch_bounds__(256) void wconv_kernel(const float* __restrict__ W,
                                                    unsigned short* __restrict__ Wb) {
    int i = blockIdx.x * 256 + threadIdx.x;
    Wb[i] = f2bf(W[i]);
}

// ---------------------------------------------------------------------------
// K3: banded causal SE-kernel matmul + fused LayerNorm, bf16 hidden out.
// 256 threads = 4 j-groups (waves) x 64 d-quads. RPB=16 rows/block.
// Wave jg handles 16 j's of each 64-j chunk with float4 emb loads
// (wave-uniform row => one contiguous 1KB transaction per j).
// ---------------------------------------------------------------------------
__global__ __launch_bounds__(256) void band_ln_kernel(
    const float* __restrict__ t, const float* __restrict__ emb,
    const float* __restrict__ gamma, const float* __restrict__ beta,
    unsigned short* __restrict__ hidden) {
    int blk = blockIdx.x;
    int b   = blk / (S / RPB);
    int i0  = (blk % (S / RPB)) * RPB;
    int tid = threadIdx.x;
    int jg  = tid >> 6;          // wave id = j-group (also score row-group)
    int dq  = tid & 63;          // d-quad (also score j-lane)
    const float* tb = t + b * S;

    float ti[RPB];
#pragma unroll
    for (int r = 0; r < RPB; ++r) ti[r] = tb[i0 + r];

    // first j with tb[j] >= tb[i0] - DT_CUT  (uniform across block)
    float tcut = ti[0] - DT_CUT;
    int lo = 0, hi = i0;
    while (lo < hi) {
        int mid = (lo + hi) >> 1;
        if (tb[mid] < tcut) lo = mid + 1; else hi = mid;
    }
    int jmin = lo;
    int jmax = i0 + RPB - 1;

    __shared__ float  s_sc[JC][RPB];        // 4 KiB scores per chunk
    __shared__ float4 s_red[4][4][64];      // 16 KiB jg-reduction buffer

    float4 acc[RPB];
#pragma unroll
    for (int r = 0; r < RPB; ++r) acc[r] = make_float4(0.f, 0.f, 0.f, 0.f);
    const float* eb = emb + (size_t)b * S * D;

    for (int j0 = jmin; j0 <= jmax; j0 += JC) {
        __syncthreads();                    // protect s_sc reuse
        {   // scores: thread (jg as row-group, dq as j-lane)
            int j  = j0 + dq;
            int jc = min(j, jmax);
            float tj = tb[jc];
            float4 sc4;
#pragma unroll
            for (int k = 0; k < 4; ++k) {
                int r = jg * 4 + k;
                float dt = ti[r] - tj;
                float sc = expf(-0.5f * dt * dt);
                ((float*)&sc4)[k] = (j <= i0 + r) ? sc : 0.0f;   // causal + tail mask
            }
            *(float4*)&s_sc[dq][jg * 4] = sc4;
        }
        __syncthreads();

#pragma unroll
        for (int jj = 0; jj < 16; ++jj) {
            int j  = j0 + jg * 16 + jj;
            int jc = min(j, jmax);          // clamped addr; score already 0 there
            float4 ev = *(const float4*)&eb[(size_t)jc * D + dq * 4];
            int jl = jg * 16 + jj;
            float4 s0 = *(const float4*)&s_sc[jl][0];
            float4 s1 = *(const float4*)&s_sc[jl][4];
            float4 s2 = *(const float4*)&s_sc[jl][8];
            float4 s3 = *(const float4*)&s_sc[jl][12];
#pragma unroll
            for (int q = 0; q < 4; ++q) {
                float4 sq = (q == 0) ? s0 : (q == 1) ? s1 : (q == 2) ? s2 : s3;
#pragma unroll
                for (int c = 0; c < 4; ++c) {
                    float s = ((float*)&sq)[c];
                    int r = q * 4 + c;
                    acc[r].x = fmaf(s, ev.x, acc[r].x);
                    acc[r].y = fmaf(s, ev.y, acc[r].y);
                    acc[r].z = fmaf(s, ev.z, acc[r].z);
                    acc[r].w = fmaf(s, ev.w, acc[r].w);
                }
            }
        }
    }

    // jg-reduction + LayerNorm, 4 rounds of 4 rows; wave jg finishes row 4g+jg
    float4 gam = *(const float4*)&gamma[dq * 4];
    float4 bet = *(const float4*)&beta[dq * 4];
    for (int g = 0; g < 4; ++g) {
        __syncthreads();
#pragma unroll
        for (int k = 0; k < 4; ++k) s_red[k][jg][dq] = acc[g * 4 + k];
        __syncthreads();
        int r = g * 4 + jg;
        float4 v0 = s_red[jg][0][dq], v1 = s_red[jg][1][dq];
        float4 v2 = s_red[jg][2][dq], v3 = s_red[jg][3][dq];
        float4 v = make_float4(v0.x + v1.x + v2.x + v3.x, v0.y + v1.y + v2.y + v3.y,
                               v0.z + v1.z + v2.z + v3.z, v0.w + v1.w + v2.w + v3.w);
        float sum = v.x + v.y + v.z + v.w;
        float sq  = v.x * v.x + v.y * v.y + v.z * v.z + v.w * v.w;
#pragma unroll
        for (int m = 32; m > 0; m >>= 1) {
            sum += __shfl_xor(sum, m);
            sq  += __shfl_xor(sq, m);
        }
        float mu   = sum * (1.0f / D);
        float var  = fmaxf(sq * (1.0f / D) - mu * mu, 0.0f);
        float rstd = rsqrtf(var + 1e-6f);
        unsigned short h4[4];
        h4[0] = f2bf((v.x - mu) * rstd * gam.x + bet.x);
        h4[1] = f2bf((v.y - mu) * rstd * gam.y + bet.y);
        h4[2] = f2bf((v.z - mu) * rstd * gam.z + bet.z);
        h4[3] = f2bf((v.w - mu) * rstd * gam.w + bet.w);
        unsigned long long packed = (unsigned long long)h4[0] |
            ((unsigned long long)h4[1] << 16) | ((unsigned long long)h4[2] << 32) |
            ((unsigned long long)h4[3] << 48);
        *(unsigned long long*)&hidden[(size_t)(b * S + i0 + r) * D + dq * 4] = packed;
    }
}

// ---------------------------------------------------------------------------
// K4: MFMA decoder. Block = 16 rows x 256 e, 4 waves (wave w = e-slice of 64).
// C[s,e] = sum_d h[s,d] * W[e,d] via mfma_f32_16x16x32_bf16; fused
// relu -> *w_t -> row-reduce -> softplus.
// ---------------------------------------------------------------------------
__global__ __launch_bounds__(256) void decoder_kernel(
    const unsigned short* __restrict__ hidden, const unsigned short* __restrict__ Wb,
    const float* __restrict__ w_t, const float* __restrict__ b_t,
    float* __restrict__ out) {
    int tid  = threadIdx.x;
    int w    = tid >> 6;
    int lane = tid & 63;
    int lr   = lane & 15;        // A-row / B-col within tile
    int lk   = lane >> 4;        // k-subgroup (8 contiguous k each)
    int row0 = blockIdx.x * 16;

    // A fragments: 8 k-tiles of hidden rows (shared by all 4 waves)
    short8 afrag[8];
    const unsigned short* hrow = hidden + (size_t)(row0 + lr) * D + lk * 8;
#pragma unroll
    for (int kt = 0; kt < 8; ++kt) afrag[kt] = *(const short8*)&hrow[kt * 32];

    f32x4 acc[4];
#pragma unroll
    for (int nt = 0; nt < 4; ++nt) acc[nt] = (f32x4){0.f, 0.f, 0.f, 0.f};

#pragma unroll
    for (int nt = 0; nt < 4; ++nt) {
        const unsigned short* wrow = Wb + (size_t)(w * 64 + nt * 16 + lr) * D + lk * 8;
#pragma unroll
        for (int kt = 0; kt < 8; ++kt) {
            short8 bfrag = *(const short8*)&wrow[kt * 32];
            acc[nt] = __builtin_amdgcn_mfma_f32_16x16x32_bf16(afrag[kt], bfrag, acc[nt], 0, 0, 0);
        }
    }

    // epilogue: relu -> *w_t -> reduce over e
    float wt[4];
#pragma unroll
    for (int nt = 0; nt < 4; ++nt) wt[nt] = w_t[w * 64 + nt * 16 + lr];
    float val[4];
#pragma unroll
    for (int reg = 0; reg < 4; ++reg) {
        float s = 0.f;
#pragma unroll
        for (int nt = 0; nt < 4; ++nt) s = fmaf(fmaxf(acc[nt][reg], 0.f), wt[nt], s);
        val[reg] = s;
    }
#pragma unroll
    for (int m = 1; m < 16; m <<= 1)
#pragma unroll
        for (int reg = 0; reg < 4; ++reg) val[reg] += __shfl_xor(val[reg], m);

    __shared__ float s_dec[4][16];
    if (lr == 0) {
#pragma unroll
        for (int reg = 0; reg < 4; ++reg) s_dec[w][lk * 4 + reg] = val[reg];
    }
    __syncthreads();
    if (tid < 16) {
        float tot = s_dec[0][tid] + s_dec[1][tid] + s_dec[2][tid] + s_dec[3][tid] + b_t[0];
        float o = fmaxf(tot, 0.0f) + log1pf(expf(-fabsf(tot)));   // softplus
        out[row0 + tid] = o;
    }
}

// ---------------------------------------------------------------------------
extern "C" void kernel_launch(void* const* d_in, const int* in_sizes, int n_in,
                              void* d_out, int out_size, void* d_ws, size_t ws_size,
                              hipStream_t stream) {
    // inputs: 0 event_type(i32) 1 event_time(f32) 2 arrival_times(f32)
    //         3 W_in 4 w_t 5 b_t 6 ln_gamma 7 ln_beta
    const float* t   = (const float*)d_in[1];
    const float* W   = (const float*)d_in[3];
    const float* wt  = (const float*)d_in[4];
    const float* bt  = (const float*)d_in[5];
    const float* gam = (const float*)d_in[6];
    const float* bet = (const float*)d_in[7];
    float* out = (float*)d_out;

    char* ws = (char*)d_ws;
    float*          emb    = (float*)ws;                        // 16 MiB
    unsigned short* hidden = (unsigned short*)(ws + (size_t)16777216);   // 8 MiB bf16
    unsigned short* Wb     = (unsigned short*)(ws + (size_t)25165824);   // 128 KiB bf16

    emb_kernel<<<dim3(BATCH * S / 2), dim3(256), 0, stream>>>(t, emb);
    wconv_kernel<<<dim3(256), dim3(256), 0, stream>>>(W, Wb);
    band_ln_kernel<<<dim3(BATCH * S / RPB), dim3(256), 0, stream>>>(t, emb, gam, bet, hidden);
    decoder_kernel<<<dim3(BATCH * S / 16), dim3(256), 0, stream>>>(hidden, Wb, wt, bt, out);
}

// Round 4
// 39.377 us; speedup vs baseline: 3.3297x; 1.8861x over previous
//
#include <hip/hip_runtime.h>
#include <hip/hip_bf16.h>
#include <math.h>

#define D 256
#define S 4096
#define BATCH 4
#define RPB 32         // rows per block in fused kernel
#define DT_CUT 7.0f

typedef __attribute__((ext_vector_type(8))) short short8;
typedef __attribute__((ext_vector_type(4))) float f32x4;

static __device__ __forceinline__ unsigned short f2bf(float x) {
    union { __hip_bfloat16 b; unsigned short u; } cv;
    cv.b = __float2bfloat16(x);    // HW RNE convert; compiler packs pairs
    return cv.u;
}

// ---------------------------------------------------------------------------
// K1: transposed bf16 sinusoidal embedding  embT[b][d][j]  (B-operand layout)
// grid = 4b x 8kg x 16jc = 512 blocks, 256 threads = j. Stores coalesced 512B.
// ---------------------------------------------------------------------------
__global__ __launch_bounds__(256) void embt_kernel(const float* __restrict__ t,
                                                   unsigned short* __restrict__ embT) {
    int blk = blockIdx.x;
    int b   = blk >> 7;
    int kg  = (blk >> 4) & 7;
    int jc  = blk & 15;
    int j   = jc * 256 + threadIdx.x;
    float tv = t[b * S + j];
    const float c2 = -0.1038102552f;           // -2*log2(10000)/256
#pragma unroll
    for (int kk = 0; kk < 16; ++kk) {
        int k = kg * 16 + kk;
        float te = tv * exp2f(c2 * (float)(k + 1));
        float sn, cs;
        __sincosf(te, &sn, &cs);
        embT[((size_t)(b * D + 2 * k)) * S + j]     = f2bf(sn);
        embT[((size_t)(b * D + 2 * k + 1)) * S + j] = f2bf(cs);
    }
}

// ---------------------------------------------------------------------------
// K2: W -> bf16 (row-major [e][d])
// ---------------------------------------------------------------------------
__global__ __launch_bounds__(256) void wconv_kernel(const float* __restrict__ W,
                                                    unsigned short* __restrict__ Wb) {
    int i = blockIdx.x * 256 + threadIdx.x;
    Wb[i] = f2bf(W[i]);
}

// ---------------------------------------------------------------------------
// K3: fused band-GEMM (MFMA) + LayerNorm + decoder-GEMM (MFMA) + softplus.
// Block = 32 rows x 256 d/e, 4 waves (wave w owns d/e slice of 64).
// Band: A = scores (computed in-reg, bf16), B = embT frags (16B contiguous).
// ---------------------------------------------------------------------------
__global__ __launch_bounds__(256) void fused_kernel(
    const float* __restrict__ t, const unsigned short* __restrict__ embT,
    const unsigned short* __restrict__ Wb,
    const float* __restrict__ gamma, const float* __restrict__ beta,
    const float* __restrict__ w_t, const float* __restrict__ b_t,
    float* __restrict__ out) {
    int blk  = blockIdx.x;
    int b    = blk >> 7;                 // 128 blocks per batch
    int i0   = (blk & 127) * RPB;
    int tid  = threadIdx.x;
    int w    = tid >> 6;
    int lane = tid & 63;
    int ln15 = lane & 15;
    int kg   = lane >> 4;
    const float* tb = t + b * S;

    float ti[2];
    ti[0] = tb[i0 + ln15];
    ti[1] = tb[i0 + 16 + ln15];

    // ---- 64-ary cooperative lower_bound: first j with t[j] >= t[i0]-DT_CUT
    float tcut = tb[i0] - DT_CUT;
    int lo = 0, hi = i0;                 // invariant: t[hi] >= tcut
    while (hi > lo) {
        int step = ((hi - lo) + 63) >> 6;
        int p = lo + lane * step;
        p = min(p, hi);
        unsigned long long mb = __ballot(tb[p] < tcut);
        int cnt = __popcll(mb);
        int nlo = (cnt == 0) ? lo : (lo + (cnt - 1) * step + 1);
        int nhi = (cnt == 0) ? nlo : min(lo + cnt * step, hi);
        lo = nlo; hi = nhi;
    }
    int jmin = lo & ~31;                 // align chunks; extra j's have score~0
    int jmax = i0 + RPB - 1;

    // ---- band GEMM: C[m, d] += scores[m, k] * embT[d, k]
    f32x4 acc[2][4];
#pragma unroll
    for (int Mt = 0; Mt < 2; ++Mt)
#pragma unroll
        for (int nt = 0; nt < 4; ++nt) acc[Mt][nt] = (f32x4){0.f, 0.f, 0.f, 0.f};

    for (int j0 = jmin; j0 <= jmax; j0 += 32) {
        float4 tja = *(const float4*)&tb[j0 + kg * 8];
        float4 tjb = *(const float4*)&tb[j0 + kg * 8 + 4];
        float tj[8] = {tja.x, tja.y, tja.z, tja.w, tjb.x, tjb.y, tjb.z, tjb.w};
        short8 af[2];
#pragma unroll
        for (int Mt = 0; Mt < 2; ++Mt) {
            union { short8 v; unsigned short u[8]; } a;
            float tiv = ti[Mt];
            int irow = i0 + Mt * 16 + ln15;
            if (j0 + 31 <= i0 + Mt * 16) {        // uniform: fully causal chunk
#pragma unroll
                for (int e = 0; e < 8; ++e) {
                    float dt = tiv - tj[e];
                    a.u[e] = f2bf(__expf(-0.5f * dt * dt));
                }
            } else {                               // diagonal chunk: mask j>i
#pragma unroll
                for (int e = 0; e < 8; ++e) {
                    float dt = tiv - tj[e];
                    float sc = __expf(-0.5f * dt * dt);
                    a.u[e] = (j0 + kg * 8 + e <= irow) ? f2bf(sc) : (unsigned short)0;
                }
            }
            af[Mt] = a.v;
        }
        const unsigned short* ebase =
            embT + ((size_t)(b * D) + w * 64 + ln15) * S + j0 + kg * 8;
#pragma unroll
        for (int nt = 0; nt < 4; ++nt) {
            short8 bf = *(const short8*)(ebase + (size_t)nt * 16 * S);
            acc[0][nt] = __builtin_amdgcn_mfma_f32_16x16x32_bf16(af[0], bf, acc[0][nt], 0, 0, 0);
            acc[1][nt] = __builtin_amdgcn_mfma_f32_16x16x32_bf16(af[1], bf, acc[1][nt], 0, 0, 0);
        }
    }

    // ---- LayerNorm (rows = Mt*16 + kg*4 + reg per lane)
    __shared__ float2 s_ln[4][RPB];
    __shared__ unsigned short H[RPB][264];       // +8 pad: conflict-free b128
    __shared__ float s_dec[4][RPB];

#pragma unroll
    for (int Mt = 0; Mt < 2; ++Mt)
#pragma unroll
        for (int reg = 0; reg < 4; ++reg) {
            float s = acc[Mt][0][reg] + acc[Mt][1][reg] + acc[Mt][2][reg] + acc[Mt][3][reg];
            float q = acc[Mt][0][reg] * acc[Mt][0][reg] + acc[Mt][1][reg] * acc[Mt][1][reg]
                    + acc[Mt][2][reg] * acc[Mt][2][reg] + acc[Mt][3][reg] * acc[Mt][3][reg];
#pragma unroll
            for (int m = 1; m < 16; m <<= 1) {
                s += __shfl_xor(s, m);
                q += __shfl_xor(q, m);
            }
            if (ln15 == 0) s_ln[w][Mt * 16 + kg * 4 + reg] = make_float2(s, q);
        }
    __syncthreads();

    float g[4], be[4];
#pragma unroll
    for (int nt = 0; nt < 4; ++nt) {
        g[nt]  = gamma[w * 64 + nt * 16 + ln15];
        be[nt] = beta[w * 64 + nt * 16 + ln15];
    }
#pragma unroll
    for (int Mt = 0; Mt < 2; ++Mt)
#pragma unroll
        for (int reg = 0; reg < 4; ++reg) {
            int r = Mt * 16 + kg * 4 + reg;
            float2 p0 = s_ln[0][r], p1 = s_ln[1][r], p2 = s_ln[2][r], p3 = s_ln[3][r];
            float sum = p0.x + p1.x + p2.x + p3.x;
            float sq  = p0.y + p1.y + p2.y + p3.y;
            float mu  = sum * (1.0f / D);
            float var = fmaxf(sq * (1.0f / D) - mu * mu, 0.0f);
            float rstd = rsqrtf(var + 1e-6f);
#pragma unroll
            for (int nt = 0; nt < 4; ++nt) {
                float h = (acc[Mt][nt][reg] - mu) * rstd * g[nt] + be[nt];
                H[r][w * 64 + nt * 16 + ln15] = f2bf(h);
            }
        }
    __syncthreads();

    // ---- decoder GEMM: C2[m, e] = sum_d H[m, d] * Wb[e, d]
    f32x4 acc2[2][4];
#pragma unroll
    for (int Mt = 0; Mt < 2; ++Mt)
#pragma unroll
        for (int et = 0; et < 4; ++et) acc2[Mt][et] = (f32x4){0.f, 0.f, 0.f, 0.f};

#pragma unroll
    for (int kt = 0; kt < 8; ++kt) {
        short8 a0 = *(const short8*)&H[ln15][kt * 32 + kg * 8];
        short8 a1 = *(const short8*)&H[16 + ln15][kt * 32 + kg * 8];
        const unsigned short* wbase = Wb + (size_t)(w * 64 + ln15) * D + kt * 32 + kg * 8;
#pragma unroll
        for (int et = 0; et < 4; ++et) {
            short8 bf = *(const short8*)(wbase + (size_t)et * 16 * D);
            acc2[0][et] = __builtin_amdgcn_mfma_f32_16x16x32_bf16(a0, bf, acc2[0][et], 0, 0, 0);
            acc2[1][et] = __builtin_amdgcn_mfma_f32_16x16x32_bf16(a1, bf, acc2[1][et], 0, 0, 0);
        }
    }

    // ---- epilogue: relu -> *w_t -> reduce over e -> softplus
    float wt[4];
#pragma unroll
    for (int et = 0; et < 4; ++et) wt[et] = w_t[w * 64 + et * 16 + ln15];
#pragma unroll
    for (int Mt = 0; Mt < 2; ++Mt)
#pragma unroll
        for (int reg = 0; reg < 4; ++reg) {
            float v = 0.f;
#pragma unroll
            for (int et = 0; et < 4; ++et)
                v = fmaf(fmaxf(acc2[Mt][et][reg], 0.f), wt[et], v);
#pragma unroll
            for (int m = 1; m < 16; m <<= 1) v += __shfl_xor(v, m);
            if (ln15 == 0) s_dec[w][Mt * 16 + kg * 4 + reg] = v;
        }
    __syncthreads();
    if (tid < RPB) {
        float tot = s_dec[0][tid] + s_dec[1][tid] + s_dec[2][tid] + s_dec[3][tid] + b_t[0];
        float o = fmaxf(tot, 0.0f) + log1pf(expf(-fabsf(tot)));   // softplus
        out[(size_t)blk * RPB + tid] = o;
    }
}

// ---------------------------------------------------------------------------
extern "C" void kernel_launch(void* const* d_in, const int* in_sizes, int n_in,
                              void* d_out, int out_size, void* d_ws, size_t ws_size,
                              hipStream_t stream) {
    // inputs: 0 event_type(i32) 1 event_time(f32) 2 arrival_times(f32)
    //         3 W_in 4 w_t 5 b_t 6 ln_gamma 7 ln_beta
    const float* t   = (const float*)d_in[1];
    const float* W   = (const float*)d_in[3];
    const float* wt  = (const float*)d_in[4];
    const float* bt  = (const float*)d_in[5];
    const float* gam = (const float*)d_in[6];
    const float* bet = (const float*)d_in[7];
    float* out = (float*)d_out;

    char* ws = (char*)d_ws;
    unsigned short* embT = (unsigned short*)ws;                       // 8 MiB
    unsigned short* Wb   = (unsigned short*)(ws + (size_t)8388608);   // 128 KiB

    embt_kernel<<<dim3(512), dim3(256), 0, stream>>>(t, embT);
    wconv_kernel<<<dim3(256), dim3(256), 0, stream>>>(W, Wb);
    fused_kernel<<<dim3(BATCH * S / RPB), dim3(256), 0, stream>>>(
        t, embT, Wb, gam, bet, wt, bt, out);
}